// Round 7
// baseline (17.755 us; speedup 1.0000x reference)
//
#include <hip/hip_runtime.h>

#define BB 64
#define KK 128
#define DD 128

typedef __attribute__((ext_vector_type(8))) short bf16x8;
typedef __attribute__((ext_vector_type(4))) float f32x4;
typedef _Float16 half2v __attribute__((ext_vector_type(2)));
typedef __fp16 fp16x2 __attribute__((ext_vector_type(2)));

__device__ __forceinline__ unsigned cvt_pk_bf16(float x, float y) {
    unsigned r;
    asm("v_cvt_pk_bf16_f32 %0, %1, %2" : "=v"(r) : "v"(x), "v"(y));
    return r;
}

__device__ __forceinline__ unsigned cvt_pkrtz_u(float x, float y) {
    const fp16x2 pk = __builtin_amdgcn_cvt_pkrtz(x, y);
    return __builtin_bit_cast(unsigned, pk);
}

// relu(a+b) on packed f16 pairs
__device__ __forceinline__ unsigned pk_add_relu(unsigned a, unsigned b) {
    unsigned s, r;
    asm("v_pk_add_f16 %0, %1, %2" : "=v"(s) : "v"(a), "v"(b));
    asm("v_pk_max_f16 %0, %1, 0" : "=v"(r) : "v"(s));
    return r;
}

__device__ __forceinline__ float dot2acc(unsigned a, unsigned b, float c) {
#if __has_builtin(__builtin_amdgcn_fdot2)
    return __builtin_amdgcn_fdot2(__builtin_bit_cast(half2v, a),
                                  __builtin_bit_cast(half2v, b), c, false);
#else
    float r;
    asm("v_dot2_f32_f16 %0, %1, %2, %3" : "=v"(r) : "v"(a), "v"(b), "v"(c));
    return r;
#endif
}

// Grid = 256 (1 block/CU), block = 256 (4 waves). Tiles: 64 i x 64 j per block.
// XCD-grouped decode: blk&7 = b>>3, so the 4 (it,jt) tiles of a given b share
// one XCD's L2 (slots halves fetched once per L2).
// No slots/W1 LDS staging: each wave loads its MFMA fragments global->reg
// (coalesced 16-row x 128B segments). Single barrier (after L/R spill).
// LDS (18560 B): LsP half2[64][36] @ word 0, RsP half2[64][36] @ word 2304,
//                W2p half2[32] @ word 4608.
//   half2 word col c holds h-pair (32*(c>>4)+(c&15), +16)
// Wave roles: side = w>>1 (0: L from slots i-tile, 1: R from slots j-tile),
//             grp = w&1 (h-half, h in [32*grp, 32*grp+32)).
__global__ __launch_bounds__(256) void fused_kernel(
    const float* __restrict__ slots, const float* __restrict__ W1,
    const float* __restrict__ b1, const float* __restrict__ W2,
    const float* __restrict__ b2p, float* __restrict__ out)
{
    __shared__ unsigned smem_w[4640];

    const int t     = threadIdx.x;
    const int blk   = blockIdx.x;
    const int xcd   = blk & 7;
    const int local = blk >> 3;              // 0..31
    const int b     = xcd * 8 + (local >> 2);
    const int it    = (local >> 1) & 1;
    const int jt    = local & 1;

    const int lane = t & 63;
    const int w    = t >> 6;                 // 0..3
    const int lr   = lane & 15;
    const int lk   = lane >> 4;
    const int side = w >> 1;                 // 0: L, 1: R
    const int grp  = w & 1;                  // h-half

    const float b2v  = *b2p;
    const float b1lo = (side == 0) ? b1[grp * 32 + lr]      : 0.0f;
    const float b1hi = (side == 0) ? b1[grp * 32 + 16 + lr] : 0.0f;

    if (t < 32) {
        const int hl = (t & 15) + 32 * (t >> 4);
        smem_w[4608 + t] = cvt_pkrtz_u(W2[hl], W2[hl + 16]);
    }

    // ---------------- B-fragments: W1 global -> reg (bf16 packed) ----------------
    bf16x8 bfr[2][4];
#pragma unroll
    for (int n = 0; n < 2; ++n)
#pragma unroll
        for (int kf = 0; kf < 4; ++kf) {
            const int rowB = grp * 32 + n * 16 + lr;
            const float* p = W1 + rowB * 256 + side * 128 + kf * 32 + lk * 8;
            const float4 f0 = *reinterpret_cast<const float4*>(p);
            const float4 f1 = *reinterpret_cast<const float4*>(p + 4);
            uint4 pk;
            pk.x = cvt_pk_bf16(f0.x, f0.y); pk.y = cvt_pk_bf16(f0.z, f0.w);
            pk.z = cvt_pk_bf16(f1.x, f1.y); pk.w = cvt_pk_bf16(f1.z, f1.w);
            bfr[n][kf] = __builtin_bit_cast(bf16x8, pk);
        }

    // ---------------- A-fragments (slots, global->reg) + MFMA, per m ----------------
    const int arow0 = (side == 0) ? it * 64 : jt * 64;
    const float* abase = slots + ((size_t)(b * KK) + arow0) * DD;

    f32x4 acc[4][2];
#pragma unroll
    for (int m = 0; m < 4; ++m)
#pragma unroll
        for (int n = 0; n < 2; ++n) acc[m][n] = f32x4{0.f, 0.f, 0.f, 0.f};

#pragma unroll
    for (int m = 0; m < 4; ++m) {
        bf16x8 af[4];
#pragma unroll
        for (int kf = 0; kf < 4; ++kf) {
            const float* p = abase + (m * 16 + lr) * DD + kf * 32 + lk * 8;
            const float4 f0 = *reinterpret_cast<const float4*>(p);
            const float4 f1 = *reinterpret_cast<const float4*>(p + 4);
            uint4 pk;
            pk.x = cvt_pk_bf16(f0.x, f0.y); pk.y = cvt_pk_bf16(f0.z, f0.w);
            pk.z = cvt_pk_bf16(f1.x, f1.y); pk.w = cvt_pk_bf16(f1.z, f1.w);
            af[kf] = __builtin_bit_cast(bf16x8, pk);
        }
#pragma unroll
        for (int kf = 0; kf < 4; ++kf) {
            acc[m][0] = __builtin_amdgcn_mfma_f32_16x16x32_bf16(af[kf], bfr[0][kf], acc[m][0], 0, 0, 0);
            acc[m][1] = __builtin_amdgcn_mfma_f32_16x16x32_bf16(af[kf], bfr[1][kf], acc[m][1], 0, 0, 0);
        }
    }

    // ---------------- spill as packed half2 (h, h+16) pairs ----------------
    {
        unsigned* dst = smem_w + (side ? 2304 : 0);
#pragma unroll
        for (int m = 0; m < 4; ++m)
#pragma unroll
            for (int r = 0; r < 4; ++r) {
                const int row = 16 * m + 4 * lk + r;     // D: row = 4*(lane>>4)+reg
                dst[row * 36 + grp * 16 + lr] =
                    cvt_pkrtz_u(acc[m][0][r] + b1lo, acc[m][1][r] + b1hi);
            }
    }
    __syncthreads();

    // ---------------- pairwise: sigmoid(b2 + sum relu(L+R)*W2) ----------------
    const int tx = t & 15;                  // j = tx + 16*jj
    const int ty = t >> 4;                  // i = ty + 16*ii
    const unsigned* LsP = smem_w;
    const unsigned* RsP = smem_w + 2304;
    const unsigned* W2p = smem_w + 4608;

    uint4 w2r[8];
#pragma unroll
    for (int s = 0; s < 8; ++s)
        w2r[s] = *reinterpret_cast<const uint4*>(W2p + s * 4);

    float pacc[4][4] = {};
    uint4 l4a[4], r4a[4], l4b[4], r4b[4];

#define LD_STEP(L4, R4, s)                                                        \
    {                                                                             \
        _Pragma("unroll") for (int ii = 0; ii < 4; ++ii)                          \
            L4[ii] = *reinterpret_cast<const uint4*>(LsP + (ty + 16 * ii) * 36 + (s) * 4); \
        _Pragma("unroll") for (int jj = 0; jj < 4; ++jj)                          \
            R4[jj] = *reinterpret_cast<const uint4*>(RsP + (tx + 16 * jj) * 36 + (s) * 4); \
    }

#define COMPUTE_STEP(L4, R4, s)                                                   \
    {                                                                             \
        _Pragma("unroll") for (int ii = 0; ii < 4; ++ii)                          \
        _Pragma("unroll") for (int jj = 0; jj < 4; ++jj) {                        \
            float a = pacc[ii][jj];                                               \
            a = dot2acc(pk_add_relu(L4[ii].x, R4[jj].x), w2r[s].x, a);            \
            a = dot2acc(pk_add_relu(L4[ii].y, R4[jj].y), w2r[s].y, a);            \
            a = dot2acc(pk_add_relu(L4[ii].z, R4[jj].z), w2r[s].z, a);            \
            a = dot2acc(pk_add_relu(L4[ii].w, R4[jj].w), w2r[s].w, a);            \
            pacc[ii][jj] = a;                                                     \
        }                                                                         \
    }

    LD_STEP(l4a, r4a, 0)
#pragma unroll
    for (int sp = 0; sp < 4; ++sp) {
        LD_STEP(l4b, r4b, 2 * sp + 1)
        COMPUTE_STEP(l4a, r4a, 2 * sp)
        if (sp < 3) LD_STEP(l4a, r4a, 2 * sp + 2)
        COMPUTE_STEP(l4b, r4b, 2 * sp + 1)
    }
#undef LD_STEP
#undef COMPUTE_STEP

#pragma unroll
    for (int ii = 0; ii < 4; ++ii) {
        const int gi = it * 64 + ty + 16 * ii;
        float* orow = out + ((size_t)(b * KK) + gi) * KK + jt * 64;
#pragma unroll
        for (int jj = 0; jj < 4; ++jj) {
            const int jl = tx + 16 * jj;
            const int gj = jt * 64 + jl;
            const float xv = pacc[ii][jj] + b2v;
            const float sg = 1.0f / (1.0f + __expf(-xv));
            orow[jl] = (gi == gj) ? 0.0f : sg;
        }
    }
}

extern "C" void kernel_launch(void* const* d_in, const int* in_sizes, int n_in,
                              void* d_out, int out_size, void* d_ws, size_t ws_size,
                              hipStream_t stream) {
    const float* slots = (const float*)d_in[0];
    const float* W1    = (const float*)d_in[1];
    const float* b1    = (const float*)d_in[2];
    const float* W2    = (const float*)d_in[3];
    const float* b2    = (const float*)d_in[4];
    float* out = (float*)d_out;
    (void)d_ws; (void)ws_size; (void)in_sizes; (void)n_in; (void)out_size;

    fused_kernel<<<BB * 4, 256, 0, stream>>>(slots, W1, b1, W2, b2, out);
}

// Round 8
// 15.331 us; speedup vs baseline: 1.1581x; 1.1581x over previous
//
#include <hip/hip_runtime.h>

#define BB 64
#define KK 128
#define DD 128

typedef __attribute__((ext_vector_type(8))) short bf16x8;
typedef __attribute__((ext_vector_type(4))) float f32x4;
typedef _Float16 half2v __attribute__((ext_vector_type(2)));
typedef __fp16 fp16x2 __attribute__((ext_vector_type(2)));

__device__ __forceinline__ unsigned cvt_pk_bf16(float x, float y) {
    unsigned r;
    asm("v_cvt_pk_bf16_f32 %0, %1, %2" : "=v"(r) : "v"(x), "v"(y));
    return r;
}

__device__ __forceinline__ unsigned cvt_pkrtz_u(float x, float y) {
    const fp16x2 pk = __builtin_amdgcn_cvt_pkrtz(x, y);
    return __builtin_bit_cast(unsigned, pk);
}

// relu(a+b) on packed f16 pairs
__device__ __forceinline__ unsigned pk_add_relu(unsigned a, unsigned b) {
    unsigned s, r;
    asm("v_pk_add_f16 %0, %1, %2" : "=v"(s) : "v"(a), "v"(b));
    asm("v_pk_max_f16 %0, %1, 0" : "=v"(r) : "v"(s));
    return r;
}

__device__ __forceinline__ float dot2acc(unsigned a, unsigned b, float c) {
#if __has_builtin(__builtin_amdgcn_fdot2)
    return __builtin_amdgcn_fdot2(__builtin_bit_cast(half2v, a),
                                  __builtin_bit_cast(half2v, b), c, false);
#else
    float r;
    asm("v_dot2_f32_f16 %0, %1, %2, %3" : "=v"(r) : "v"(a), "v"(b), "v"(c));
    return r;
#endif
}

// Grid = 256 (1 block/CU), block = 512 (8 waves, 2/SIMD). Out tile 64i x 64j.
// LDS (51328 B, disjoint regions, 2 barriers total):
//   SA  bf16[128][128] @ byte 0      rows 0-63: slots i-tile, 64-127: j-tile
//       XOR-swizzled per 16B block: blk' = blk ^ (row & 7)
//   LsP half2[64][36] @ word 8192, RsP half2[64][36] @ word 10496,
//   W2p half2[32]     @ word 12800
//   half2 word col c holds h-pair (32*(c>>4)+(c&15), +16)
// W1 is never staged: each wave loads its B-fragments global->reg before the
// staging barrier (latency hidden under slots staging).
// Wave roles: w = side*4 + grp*2 + mh
//   side: 0=L (slots i-tile rows), 1=R (slots j-tile rows)
//   grp : h-half, h in [32*grp, 32*grp+32)  (both 16-col pairs in-reg)
//   mh  : which 32-row half of the 64-row side tile
__global__ __launch_bounds__(512, 2) void fused_kernel(
    const float* __restrict__ slots, const float* __restrict__ W1,
    const float* __restrict__ b1, const float* __restrict__ W2,
    const float* __restrict__ b2p, float* __restrict__ out)
{
    __shared__ unsigned smem_w[12832];
    char* smem = (char*)smem_w;

    const int t   = threadIdx.x;
    const int blk = blockIdx.x;
    const int b   = blk >> 2;
    const int it  = (blk >> 1) & 1;
    const int jt  = blk & 1;

    const int lane = t & 63;
    const int w    = t >> 6;                 // 0..7
    const int lr   = lane & 15;
    const int lk   = lane >> 4;
    const int side = w >> 2;                 // 0: L, 1: R
    const int grp  = (w >> 1) & 1;           // h-half
    const int mh   = w & 1;                  // 32-row half of side tile

    const float b2v  = *b2p;
    const float b1lo = (side == 0) ? b1[grp * 32 + lr]      : 0.0f;
    const float b1hi = (side == 0) ? b1[grp * 32 + 16 + lr] : 0.0f;

    if (t < 32) {
        const int hl = (t & 15) + 32 * (t >> 4);
        smem_w[12800 + t] = cvt_pkrtz_u(W2[hl], W2[hl + 16]);
    }

    // ---------------- B-fragments: W1 global -> reg (issued pre-barrier) ----------
    bf16x8 bfr[2][4];
#pragma unroll
    for (int n = 0; n < 2; ++n)
#pragma unroll
        for (int kf = 0; kf < 4; ++kf) {
            const int rowB = grp * 32 + n * 16 + lr;
            const float* p = W1 + rowB * 256 + side * 128 + kf * 32 + lk * 8;
            const float4 f0 = *reinterpret_cast<const float4*>(p);
            const float4 f1 = *reinterpret_cast<const float4*>(p + 4);
            uint4 pk;
            pk.x = cvt_pk_bf16(f0.x, f0.y); pk.y = cvt_pk_bf16(f0.z, f0.w);
            pk.z = cvt_pk_bf16(f1.x, f1.y); pk.w = cvt_pk_bf16(f1.z, f1.w);
            bfr[n][kf] = __builtin_bit_cast(bf16x8, pk);
        }

    // ---------------- stage slots tiles as swizzled bf16 ----------------
    {
        const float* srcI = slots + ((size_t)(b * KK) + it * 64) * DD;
        const float* srcJ = slots + ((size_t)(b * KK) + jt * 64) * DD;
#pragma unroll
        for (int x0 = 0; x0 < 2048; x0 += 512) {          // 128 rows x 16 16B-blocks
            const int x = x0 + t;
            const int row = x >> 4, cb = x & 15;
            const float* src = (row < 64 ? srcI + row * DD
                                         : srcJ + (row - 64) * DD) + cb * 8;
            const float4 f0 = *reinterpret_cast<const float4*>(src);
            const float4 f1 = *reinterpret_cast<const float4*>(src + 4);
            uint4 pk;
            pk.x = cvt_pk_bf16(f0.x, f0.y); pk.y = cvt_pk_bf16(f0.z, f0.w);
            pk.z = cvt_pk_bf16(f1.x, f1.y); pk.w = cvt_pk_bf16(f1.z, f1.w);
            *reinterpret_cast<uint4*>(smem + row * 256 + ((cb ^ (row & 7)) << 4)) = pk;
        }
    }
    __syncthreads();

    // ---------------- MFMA + spill (one phase, disjoint LDS regions) -------------
    f32x4 acc[2][2];
#pragma unroll
    for (int m = 0; m < 2; ++m)
#pragma unroll
        for (int n = 0; n < 2; ++n) acc[m][n] = f32x4{0.f, 0.f, 0.f, 0.f};

#pragma unroll
    for (int m = 0; m < 2; ++m)
#pragma unroll
        for (int kf = 0; kf < 4; ++kf) {
            const int row = side * 64 + mh * 32 + m * 16 + lr;
            const int cb  = kf * 4 + lk;
            const bf16x8 af = *reinterpret_cast<const bf16x8*>(
                smem + row * 256 + ((cb ^ (row & 7)) << 4));
            acc[m][0] = __builtin_amdgcn_mfma_f32_16x16x32_bf16(af, bfr[0][kf], acc[m][0], 0, 0, 0);
            acc[m][1] = __builtin_amdgcn_mfma_f32_16x16x32_bf16(af, bfr[1][kf], acc[m][1], 0, 0, 0);
        }

    {
        unsigned* dst = smem_w + (side ? 10496 : 8192);
#pragma unroll
        for (int m = 0; m < 2; ++m)
#pragma unroll
            for (int r = 0; r < 4; ++r) {
                const int row = mh * 32 + 16 * m + 4 * lk + r;   // D: row=4*(lane>>4)+reg
                dst[row * 36 + grp * 16 + lr] =
                    cvt_pkrtz_u(acc[m][0][r] + b1lo, acc[m][1][r] + b1hi);
            }
    }
    __syncthreads();

    // ---------------- pairwise: sigmoid(b2 + sum relu(L+R)*W2) ----------------
    const int tx = t & 15;                  // j = tx + 16*jj (jj<4)
    const int ty = t >> 4;                  // i = ty + 32*ii (ii<2)
    const unsigned* LsP = smem_w + 8192;
    const unsigned* RsP = smem_w + 10496;
    const unsigned* W2p = smem_w + 12800;

    uint4 w2r[8];
#pragma unroll
    for (int s = 0; s < 8; ++s)
        w2r[s] = *reinterpret_cast<const uint4*>(W2p + s * 4);

    float pacc[2][4] = {};
    uint4 l4a[2], r4a[4], l4b[2], r4b[4];

#define LD_STEP(L4, R4, s)                                                        \
    {                                                                             \
        _Pragma("unroll") for (int ii = 0; ii < 2; ++ii)                          \
            L4[ii] = *reinterpret_cast<const uint4*>(LsP + (ty + 32 * ii) * 36 + (s) * 4); \
        _Pragma("unroll") for (int jj = 0; jj < 4; ++jj)                          \
            R4[jj] = *reinterpret_cast<const uint4*>(RsP + (tx + 16 * jj) * 36 + (s) * 4); \
    }

#define COMPUTE_STEP(L4, R4, s)                                                   \
    {                                                                             \
        _Pragma("unroll") for (int ii = 0; ii < 2; ++ii)                          \
        _Pragma("unroll") for (int jj = 0; jj < 4; ++jj) {                        \
            float a = pacc[ii][jj];                                               \
            a = dot2acc(pk_add_relu(L4[ii].x, R4[jj].x), w2r[s].x, a);            \
            a = dot2acc(pk_add_relu(L4[ii].y, R4[jj].y), w2r[s].y, a);            \
            a = dot2acc(pk_add_relu(L4[ii].z, R4[jj].z), w2r[s].z, a);            \
            a = dot2acc(pk_add_relu(L4[ii].w, R4[jj].w), w2r[s].w, a);            \
            pacc[ii][jj] = a;                                                     \
        }                                                                         \
    }

    LD_STEP(l4a, r4a, 0)
#pragma unroll
    for (int sp = 0; sp < 4; ++sp) {
        LD_STEP(l4b, r4b, 2 * sp + 1)
        COMPUTE_STEP(l4a, r4a, 2 * sp)
        if (sp < 3) LD_STEP(l4a, r4a, 2 * sp + 2)
        COMPUTE_STEP(l4b, r4b, 2 * sp + 1)
    }
#undef LD_STEP
#undef COMPUTE_STEP

#pragma unroll
    for (int ii = 0; ii < 2; ++ii) {
        const int gi = it * 64 + ty + 32 * ii;
        float* orow = out + ((size_t)(b * KK) + gi) * KK + jt * 64;
#pragma unroll
        for (int jj = 0; jj < 4; ++jj) {
            const int jl = tx + 16 * jj;
            const int gj = jt * 64 + jl;
            const float xv = pacc[ii][jj] + b2v;
            const float sg = 1.0f / (1.0f + __expf(-xv));
            orow[jl] = (gi == gj) ? 0.0f : sg;
        }
    }
}

extern "C" void kernel_launch(void* const* d_in, const int* in_sizes, int n_in,
                              void* d_out, int out_size, void* d_ws, size_t ws_size,
                              hipStream_t stream) {
    const float* slots = (const float*)d_in[0];
    const float* W1    = (const float*)d_in[1];
    const float* b1    = (const float*)d_in[2];
    const float* W2    = (const float*)d_in[3];
    const float* b2    = (const float*)d_in[4];
    float* out = (float*)d_out;
    (void)d_ws; (void)ws_size; (void)in_sizes; (void)n_in; (void)out_size;

    fused_kernel<<<BB * 4, 512, 0, stream>>>(slots, W1, b1, W2, b2, out);
}

// Round 9
// 13.220 us; speedup vs baseline: 1.3430x; 1.1597x over previous
//
#include <hip/hip_runtime.h>

#define BB 64
#define KK 128
#define DD 128

typedef __attribute__((ext_vector_type(8))) short bf16x8;
typedef __attribute__((ext_vector_type(4))) float f32x4;
typedef _Float16 half2v __attribute__((ext_vector_type(2)));
typedef __fp16 fp16x2 __attribute__((ext_vector_type(2)));

__device__ __forceinline__ unsigned cvt_pk_bf16(float x, float y) {
    unsigned r;
    asm("v_cvt_pk_bf16_f32 %0, %1, %2" : "=v"(r) : "v"(x), "v"(y));
    return r;
}

__device__ __forceinline__ unsigned cvt_pkrtz_u(float x, float y) {
    const fp16x2 pk = __builtin_amdgcn_cvt_pkrtz(x, y);
    return __builtin_bit_cast(unsigned, pk);
}

// relu(a+b) on packed f16 pairs
__device__ __forceinline__ unsigned pk_add_relu(unsigned a, unsigned b) {
    unsigned s, r;
    asm("v_pk_add_f16 %0, %1, %2" : "=v"(s) : "v"(a), "v"(b));
    asm("v_pk_max_f16 %0, %1, 0" : "=v"(r) : "v"(s));
    return r;
}

__device__ __forceinline__ float dot2acc(unsigned a, unsigned b, float c) {
#if __has_builtin(__builtin_amdgcn_fdot2)
    return __builtin_amdgcn_fdot2(__builtin_bit_cast(half2v, a),
                                  __builtin_bit_cast(half2v, b), c, false);
#else
    float r;
    asm("v_dot2_f32_f16 %0, %1, %2, %3" : "=v"(r) : "v"(a), "v"(b), "v"(c));
    return r;
#endif
}

// R5 skeleton + R8's LDS-local micro-opts. Grid = 256 (1 block/CU), block =
// 512 threads (8 waves, 2/SIMD). Out tile 64i x 64j per block.
// LDS map (64 KiB union, barrier-separated, 3 barriers):
//  phase A: SA  bf16[128][128] @ 0      (rows 0-63: slots i-tile, 64-127: j-tile)
//           W1s bf16[64][256]  @ 32768
//           both XOR-swizzled per 16B block: blk' = blk ^ (row & 7)
//  phase B: LsP half2[64][36] @ word 0, RsP half2[64][36] @ word 2304,
//           W2p half2[32] @ word 4608
//           half2 word col c holds h-pair (32*(c>>4)+(c&15), +16)
// Wave roles (w = 0..7): side = w>>2 (0: L / i-tile, 1: R / j-tile),
//   grp = (w>>1)&1 (h-half, both 16-col pairs in-reg), mh = w&1 (32-row half).
__global__ __launch_bounds__(512, 2) void fused_kernel(
    const float* __restrict__ slots, const float* __restrict__ W1,
    const float* __restrict__ b1, const float* __restrict__ W2,
    const float* __restrict__ b2p, float* __restrict__ out)
{
    __shared__ unsigned smem_w[16384];           // 65536 B
    char* smem = (char*)smem_w;

    const int t   = threadIdx.x;
    const int blk = blockIdx.x;
    const int b   = blk >> 2;
    const int it  = (blk >> 1) & 1;
    const int jt  = blk & 1;

    const int lane = t & 63;
    const int w    = t >> 6;                 // 0..7
    const int lr   = lane & 15;
    const int lk   = lane >> 4;
    const int side = w >> 2;                 // 0: L, 1: R
    const int grp  = (w >> 1) & 1;           // h-half
    const int mh   = w & 1;                  // 32-row half of the side tile

    const float b2v  = *b2p;
    const float b1lo = (side == 0) ? b1[grp * 32 + lr]      : 0.0f;
    const float b1hi = (side == 0) ? b1[grp * 32 + 16 + lr] : 0.0f;
    float w2lo = 0.f, w2hi = 0.f;
    if (t < 32) {
        const int hl = (t & 15) + 32 * (t >> 4);
        w2lo = W2[hl]; w2hi = W2[hl + 16];
    }

    // ---------------- stage SA + W1 as swizzled bf16 ----------------
    {
        const float* srcI = slots + ((size_t)(b * KK) + it * 64) * DD;
        const float* srcJ = slots + ((size_t)(b * KK) + jt * 64) * DD;
#pragma unroll
        for (int x0 = 0; x0 < 2048; x0 += 512) {           // 128 rows x 16 16B-blocks
            const int x = x0 + t;
            const int row = x >> 4, cb = x & 15;
            const float* src = (row < 64 ? srcI + row * DD
                                         : srcJ + (row - 64) * DD) + cb * 8;
            const float4 f0 = *reinterpret_cast<const float4*>(src);
            const float4 f1 = *reinterpret_cast<const float4*>(src + 4);
            uint4 pk;
            pk.x = cvt_pk_bf16(f0.x, f0.y); pk.y = cvt_pk_bf16(f0.z, f0.w);
            pk.z = cvt_pk_bf16(f1.x, f1.y); pk.w = cvt_pk_bf16(f1.z, f1.w);
            *reinterpret_cast<uint4*>(smem + row * 256 + ((cb ^ (row & 7)) << 4)) = pk;
        }
#pragma unroll
        for (int x0 = 0; x0 < 2048; x0 += 512) {           // 64 rows x 32 16B-blocks
            const int x = x0 + t;
            const int row = x >> 5, cb = x & 31;
            const float* src = W1 + row * 256 + cb * 8;
            const float4 f0 = *reinterpret_cast<const float4*>(src);
            const float4 f1 = *reinterpret_cast<const float4*>(src + 4);
            uint4 pk;
            pk.x = cvt_pk_bf16(f0.x, f0.y); pk.y = cvt_pk_bf16(f0.z, f0.w);
            pk.z = cvt_pk_bf16(f1.x, f1.y); pk.w = cvt_pk_bf16(f1.z, f1.w);
            *reinterpret_cast<uint4*>(smem + 32768 + row * 512 + ((cb ^ (row & 7)) << 4)) = pk;
        }
    }
    __syncthreads();

    // ---------------- MFMA: wave = side x h-half x row-half ----------------
    bf16x8 bfr[2][4];
#pragma unroll
    for (int n = 0; n < 2; ++n)
#pragma unroll
        for (int kf = 0; kf < 4; ++kf) {
            const int rowB = grp * 32 + n * 16 + lr;
            const int cb   = side * 16 + kf * 4 + lk;
            bfr[n][kf] = *reinterpret_cast<const bf16x8*>(
                smem + 32768 + rowB * 512 + ((cb ^ (rowB & 7)) << 4));
        }

    f32x4 acc[2][2];
#pragma unroll
    for (int m = 0; m < 2; ++m)
#pragma unroll
        for (int n = 0; n < 2; ++n) acc[m][n] = f32x4{0.f, 0.f, 0.f, 0.f};

#pragma unroll
    for (int m = 0; m < 2; ++m)
#pragma unroll
        for (int kf = 0; kf < 4; ++kf) {
            const int row = side * 64 + mh * 32 + m * 16 + lr;
            const int cb  = kf * 4 + lk;
            const bf16x8 af = *reinterpret_cast<const bf16x8*>(
                smem + row * 256 + ((cb ^ (row & 7)) << 4));
            acc[m][0] = __builtin_amdgcn_mfma_f32_16x16x32_bf16(af, bfr[0][kf], acc[m][0], 0, 0, 0);
            acc[m][1] = __builtin_amdgcn_mfma_f32_16x16x32_bf16(af, bfr[1][kf], acc[m][1], 0, 0, 0);
        }
    __syncthreads();

    // ---------------- spill as packed half2 (h, h+16) pairs, single b32 ----------
    {
        unsigned* dst = smem_w + (side ? 2304 : 0);
#pragma unroll
        for (int m = 0; m < 2; ++m)
#pragma unroll
            for (int r = 0; r < 4; ++r) {
                const int row = mh * 32 + 16 * m + 4 * lk + r;   // D: row=4*(lane>>4)+reg
                dst[row * 36 + grp * 16 + lr] =
                    cvt_pkrtz_u(acc[m][0][r] + b1lo, acc[m][1][r] + b1hi);
            }
        if (t < 32) smem_w[4608 + t] = cvt_pkrtz_u(w2lo, w2hi);
    }
    __syncthreads();

    // ---------------- pairwise: sigmoid(b2 + sum relu(L+R)*W2) ----------------
    const int tx = t & 15;                  // j = tx + 16*jj (jj<4)
    const int ty = t >> 4;                  // i = ty + 32*ii (ii<2)
    const unsigned* LsP = smem_w;
    const unsigned* RsP = smem_w + 2304;
    const unsigned* W2p = smem_w + 4608;

    uint4 w2r[8];
#pragma unroll
    for (int s = 0; s < 8; ++s)
        w2r[s] = *reinterpret_cast<const uint4*>(W2p + s * 4);

    float pacc[2][4] = {};
    uint4 l4a[2], r4a[4], l4b[2], r4b[4];

#define LD_STEP(L4, R4, s)                                                        \
    {                                                                             \
        _Pragma("unroll") for (int ii = 0; ii < 2; ++ii)                          \
            L4[ii] = *reinterpret_cast<const uint4*>(LsP + (ty + 32 * ii) * 36 + (s) * 4); \
        _Pragma("unroll") for (int jj = 0; jj < 4; ++jj)                          \
            R4[jj] = *reinterpret_cast<const uint4*>(RsP + (tx + 16 * jj) * 36 + (s) * 4); \
    }

#define COMPUTE_STEP(L4, R4, s)                                                   \
    {                                                                             \
        _Pragma("unroll") for (int ii = 0; ii < 2; ++ii)                          \
        _Pragma("unroll") for (int jj = 0; jj < 4; ++jj) {                        \
            float a = pacc[ii][jj];                                               \
            a = dot2acc(pk_add_relu(L4[ii].x, R4[jj].x), w2r[s].x, a);            \
            a = dot2acc(pk_add_relu(L4[ii].y, R4[jj].y), w2r[s].y, a);            \
            a = dot2acc(pk_add_relu(L4[ii].z, R4[jj].z), w2r[s].z, a);            \
            a = dot2acc(pk_add_relu(L4[ii].w, R4[jj].w), w2r[s].w, a);            \
            pacc[ii][jj] = a;                                                     \
        }                                                                         \
    }

    LD_STEP(l4a, r4a, 0)
#pragma unroll
    for (int sp = 0; sp < 4; ++sp) {
        LD_STEP(l4b, r4b, 2 * sp + 1)
        COMPUTE_STEP(l4a, r4a, 2 * sp)
        if (sp < 3) LD_STEP(l4a, r4a, 2 * sp + 2)
        COMPUTE_STEP(l4b, r4b, 2 * sp + 1)
    }
#undef LD_STEP
#undef COMPUTE_STEP

#pragma unroll
    for (int ii = 0; ii < 2; ++ii) {
        const int gi = it * 64 + ty + 32 * ii;
        float* orow = out + ((size_t)(b * KK) + gi) * KK + jt * 64;
#pragma unroll
        for (int jj = 0; jj < 4; ++jj) {
            const int jl = tx + 16 * jj;
            const int gj = jt * 64 + jl;
            const float xv = pacc[ii][jj] + b2v;
            const float sg = 1.0f / (1.0f + __expf(-xv));
            orow[jl] = (gi == gj) ? 0.0f : sg;
        }
    }
}

extern "C" void kernel_launch(void* const* d_in, const int* in_sizes, int n_in,
                              void* d_out, int out_size, void* d_ws, size_t ws_size,
                              hipStream_t stream) {
    const float* slots = (const float*)d_in[0];
    const float* W1    = (const float*)d_in[1];
    const float* b1    = (const float*)d_in[2];
    const float* W2    = (const float*)d_in[3];
    const float* b2    = (const float*)d_in[4];
    float* out = (float*)d_out;
    (void)d_ws; (void)ws_size; (void)in_sizes; (void)n_in; (void)out_size;

    fused_kernel<<<BB * 4, 512, 0, stream>>>(slots, W1, b1, W2, b2, out);
}

// Round 10
// 12.567 us; speedup vs baseline: 1.4128x; 1.0520x over previous
//
#include <hip/hip_runtime.h>

#define BB 64
#define KK 128
#define DD 128

typedef __attribute__((ext_vector_type(8))) short bf16x8;
typedef __attribute__((ext_vector_type(4))) float f32x4;
typedef _Float16 half2v __attribute__((ext_vector_type(2)));
typedef __fp16 fp16x2 __attribute__((ext_vector_type(2)));

__device__ __forceinline__ unsigned cvt_pk_bf16(float x, float y) {
    unsigned r;
    asm("v_cvt_pk_bf16_f32 %0, %1, %2" : "=v"(r) : "v"(x), "v"(y));
    return r;
}

__device__ __forceinline__ unsigned cvt_pkrtz_u(float x, float y) {
    const fp16x2 pk = __builtin_amdgcn_cvt_pkrtz(x, y);
    return __builtin_bit_cast(unsigned, pk);
}

// relu(a+b) on packed f16 pairs
__device__ __forceinline__ unsigned pk_add_relu(unsigned a, unsigned b) {
    unsigned s, r;
    asm("v_pk_add_f16 %0, %1, %2" : "=v"(s) : "v"(a), "v"(b));
    asm("v_pk_max_f16 %0, %1, 0" : "=v"(r) : "v"(s));
    return r;
}

__device__ __forceinline__ float dot2acc(unsigned a, unsigned b, float c) {
#if __has_builtin(__builtin_amdgcn_fdot2)
    return __builtin_amdgcn_fdot2(__builtin_bit_cast(half2v, a),
                                  __builtin_bit_cast(half2v, b), c, false);
#else
    float r;
    asm("v_dot2_f32_f16 %0, %1, %2, %3" : "=v"(r) : "v"(a), "v"(b), "v"(c));
    return r;
#endif
}

// Block = 512 threads (8 waves, 2/SIMD), grid = 256 (1 block/CU, zero redundancy).
// LDS map (64 KiB union, barrier-separated):
//  phase A: SA  bf16[128][128] @ 0      (rows 0-63: slots i-tile, 64-127: j-tile)
//           W1s bf16[64][256]  @ 32768
//           both XOR-swizzled per 16B block: blk' = blk ^ (row & 7)
//  phase B: LsP half2[64][36] @ word 0, RsP half2[64][36] @ word 2304,
//           W2p half2[32] @ word 4608
//           half2 word c holds h-pair (32*(c>>4)+(c&15), +16)
// MFMA specialization: wave w -> side = w>>2 (L/R), hq = w&3 (16-wide h slice).
__global__ __launch_bounds__(512, 2) void fused_kernel(
    const float* __restrict__ slots, const float* __restrict__ W1,
    const float* __restrict__ b1, const float* __restrict__ W2,
    const float* __restrict__ b2p, float* __restrict__ out)
{
    __shared__ unsigned smem_w[16384];           // 65536 B
    char* smem = (char*)smem_w;

    const int t   = threadIdx.x;
    const int blk = blockIdx.x;
    const int b   = blk >> 2;
    const int it  = (blk >> 1) & 1;
    const int jt  = blk & 1;

    const int lane = t & 63;
    const int w    = t >> 6;                     // 0..7
    const int lr   = lane & 15;
    const int lk   = lane >> 4;
    const int side = w >> 2;                     // 0: L-GEMM, 1: R-GEMM
    const int hq   = w & 3;                      // h slice [16*hq, 16*hq+16)

    const float badd = (side == 0) ? b1[hq * 16 + lr] : 0.0f;
    float w2lo = 0.f, w2hi = 0.f;
    if (t < 32) {
        const int hl = (t & 15) + 32 * (t >> 4);
        w2lo = W2[hl]; w2hi = W2[hl + 16];
    }

    // ---------------- stage SA + W1 as swizzled bf16 ----------------
    {
        const float* srcI = slots + ((size_t)(b * KK) + it * 64) * DD;
        const float* srcJ = slots + ((size_t)(b * KK) + jt * 64) * DD;
#pragma unroll
        for (int x0 = 0; x0 < 2048; x0 += 512) {           // 128 rows x 16 16B-blocks
            const int x = x0 + t;
            const int row = x >> 4, cb = x & 15;
            const float* src = (row < 64 ? srcI + row * DD
                                         : srcJ + (row - 64) * DD) + cb * 8;
            const float4 f0 = *reinterpret_cast<const float4*>(src);
            const float4 f1 = *reinterpret_cast<const float4*>(src + 4);
            uint4 pk;
            pk.x = cvt_pk_bf16(f0.x, f0.y); pk.y = cvt_pk_bf16(f0.z, f0.w);
            pk.z = cvt_pk_bf16(f1.x, f1.y); pk.w = cvt_pk_bf16(f1.z, f1.w);
            *reinterpret_cast<uint4*>(smem + row * 256 + ((cb ^ (row & 7)) << 4)) = pk;
        }
#pragma unroll
        for (int x0 = 0; x0 < 2048; x0 += 512) {           // 64 rows x 32 16B-blocks
            const int x = x0 + t;
            const int row = x >> 5, cb = x & 31;
            const float* src = W1 + row * 256 + cb * 8;
            const float4 f0 = *reinterpret_cast<const float4*>(src);
            const float4 f1 = *reinterpret_cast<const float4*>(src + 4);
            uint4 pk;
            pk.x = cvt_pk_bf16(f0.x, f0.y); pk.y = cvt_pk_bf16(f0.z, f0.w);
            pk.z = cvt_pk_bf16(f1.x, f1.y); pk.w = cvt_pk_bf16(f1.z, f1.w);
            *reinterpret_cast<uint4*>(smem + 32768 + row * 512 + ((cb ^ (row & 7)) << 4)) = pk;
        }
    }
    __syncthreads();

    // ---------------- MFMA: wave = side x h-quarter ----------------
    bf16x8 bfr[4];
#pragma unroll
    for (int kf = 0; kf < 4; ++kf) {
        const int rowB = hq * 16 + lr;
        const int cb   = side * 16 + kf * 4 + lk;
        bfr[kf] = *reinterpret_cast<const bf16x8*>(
            smem + 32768 + rowB * 512 + ((cb ^ (rowB & 7)) << 4));
    }
    f32x4 acc[4];
#pragma unroll
    for (int m = 0; m < 4; ++m) acc[m] = f32x4{0.f, 0.f, 0.f, 0.f};
#pragma unroll
    for (int m = 0; m < 4; ++m) {
#pragma unroll
        for (int kf = 0; kf < 4; ++kf) {
            const int row = side * 64 + 16 * m + lr;
            const int cb  = kf * 4 + lk;
            const bf16x8 af = *reinterpret_cast<const bf16x8*>(
                smem + row * 256 + ((cb ^ (row & 7)) << 4));
            acc[m] = __builtin_amdgcn_mfma_f32_16x16x32_bf16(af, bfr[kf], acc[m], 0, 0, 0);
        }
    }
    __syncthreads();

    // ---------------- spill as f16 halves into (h, h+16) word layout ----------------
    {
        __fp16* dst = (__fp16*)smem + (side ? 4608 : 0);   // L words 0.., R words 2304..
        const int g  = hq >> 1;
        const int hl = hq & 1;
#pragma unroll
        for (int m = 0; m < 4; ++m)
#pragma unroll
            for (int r = 0; r < 4; ++r) {
                const int row = 16 * m + 4 * lk + r;       // D: row = 4*(lane>>4)+reg
                dst[(row * 36 + g * 16 + lr) * 2 + hl] = (__fp16)(acc[m][r] + badd);
            }
        if (t < 32) ((unsigned*)smem)[4608 + t] = cvt_pkrtz_u(w2lo, w2hi);
    }
    __syncthreads();

    // ---------------- pairwise: sigmoid(b2 + sum relu(L+R)*W2) ----------------
    const int tx = t & 15;                  // j = tx + 16*jj
    const int ty = t >> 4;                  // i = ty + 32*ii  (ty 0..31)
    const unsigned* LsP = (const unsigned*)smem;
    const unsigned* RsP = LsP + 2304;
    const unsigned* W2p = LsP + 4608;

    uint4 w2r[8];
#pragma unroll
    for (int s = 0; s < 8; ++s)
        w2r[s] = *reinterpret_cast<const uint4*>(W2p + s * 4);

    float pacc[2][4] = {};
    uint4 l4a[2], r4a[4], l4b[2], r4b[4];

#define LD_STEP(L4, R4, s)                                                        \
    {                                                                             \
        _Pragma("unroll") for (int ii = 0; ii < 2; ++ii)                          \
            L4[ii] = *reinterpret_cast<const uint4*>(LsP + (ty + 32 * ii) * 36 + (s) * 4); \
        _Pragma("unroll") for (int jj = 0; jj < 4; ++jj)                          \
            R4[jj] = *reinterpret_cast<const uint4*>(RsP + (tx + 16 * jj) * 36 + (s) * 4); \
    }

#define COMPUTE_STEP(L4, R4, s)                                                   \
    {                                                                             \
        _Pragma("unroll") for (int ii = 0; ii < 2; ++ii)                          \
        _Pragma("unroll") for (int jj = 0; jj < 4; ++jj) {                        \
            float a = pacc[ii][jj];                                               \
            a = dot2acc(pk_add_relu(L4[ii].x, R4[jj].x), w2r[s].x, a);            \
            a = dot2acc(pk_add_relu(L4[ii].y, R4[jj].y), w2r[s].y, a);            \
            a = dot2acc(pk_add_relu(L4[ii].z, R4[jj].z), w2r[s].z, a);            \
            a = dot2acc(pk_add_relu(L4[ii].w, R4[jj].w), w2r[s].w, a);            \
            pacc[ii][jj] = a;                                                     \
        }                                                                         \
    }

    LD_STEP(l4a, r4a, 0)
#pragma unroll
    for (int sp = 0; sp < 4; ++sp) {
        LD_STEP(l4b, r4b, 2 * sp + 1)
        COMPUTE_STEP(l4a, r4a, 2 * sp)
        if (sp < 3) LD_STEP(l4a, r4a, 2 * sp + 2)
        COMPUTE_STEP(l4b, r4b, 2 * sp + 1)
    }
#undef LD_STEP
#undef COMPUTE_STEP

    const float b2 = *b2p;
#pragma unroll
    for (int ii = 0; ii < 2; ++ii) {
        const int gi = it * 64 + ty + 32 * ii;
        float* orow = out + ((size_t)(b * KK) + gi) * KK + jt * 64;
#pragma unroll
        for (int jj = 0; jj < 4; ++jj) {
            const int jl = tx + 16 * jj;
            const int gj = jt * 64 + jl;
            const float xv = pacc[ii][jj] + b2;
            const float sg = 1.0f / (1.0f + __expf(-xv));
            orow[jl] = (gi == gj) ? 0.0f : sg;
        }
    }
}

extern "C" void kernel_launch(void* const* d_in, const int* in_sizes, int n_in,
                              void* d_out, int out_size, void* d_ws, size_t ws_size,
                              hipStream_t stream) {
    const float* slots = (const float*)d_in[0];
    const float* W1    = (const float*)d_in[1];
    const float* b1    = (const float*)d_in[2];
    const float* W2    = (const float*)d_in[3];
    const float* b2    = (const float*)d_in[4];
    float* out = (float*)d_out;
    (void)d_ws; (void)ws_size; (void)in_sizes; (void)n_in; (void)out_size;

    fused_kernel<<<BB * 4, 512, 0, stream>>>(slots, W1, b1, W2, b2, out);
}